// Round 1
// 219.544 us; speedup vs baseline: 1.0088x; 1.0088x over previous
//
#include <hip/hip_runtime.h>
#include <hip/hip_bf16.h>
#include <stdint.h>

#define E_ 768
#define H_ 768
#define C_ 9
#define M_TOTAL 32768
#define BM_ 64           // tokens per block

typedef __attribute__((ext_vector_type(8))) __bf16 bf16x8;
typedef __attribute__((ext_vector_type(4))) float f32x4;
typedef __attribute__((ext_vector_type(4))) int i32x4;

static_assert(sizeof(bf16x8) == 16, "bf16x8 must be 16B");

__device__ __forceinline__ unsigned short f2bf(float f) {
    __hip_bfloat16 h = __float2bfloat16(f);
    return __builtin_bit_cast(unsigned short, h);
}

// ---------------------------------------------------------------------------
// Prep (unchanged): W1 -> bf16 B-fragment cells, ntile-major; W2 -> padded
// B-frag cells; loss zeroed.
//   W1f[((ntile*24 + t)*64 + lane)*8 + j] = bf16(W1[k][n])
//     ntile=n>>4, t=k>>5, lane=(n&15)+16*((k>>3)&3), j=k&7
// ---------------------------------------------------------------------------
__global__ void prep_kernel(const float* __restrict__ W1, const float* __restrict__ W2,
                            unsigned short* __restrict__ W1f, unsigned short* __restrict__ W2f,
                            float* __restrict__ loss_out)
{
    int b = blockIdx.x;
    int n = threadIdx.x;
    if (b < 768) {
        int k = b;
        float v = W1[k * H_ + n];
        int ntile = n >> 4;
        int t = k >> 5;
        int lane = (n & 15) + 16 * ((k >> 3) & 3);
        int j = k & 7;
        W1f[((ntile * 24 + t) * 64 + lane) * 8 + j] = f2bf(v);
    } else {
        for (int it = 0; it < 16; ++it) {
            int tid = it * 768 + n;
            int j    = tid & 7;
            int lane = (tid >> 3) & 63;
            int t    = tid >> 9;
            int cls  = lane & 15;
            int k = t * 32 + (lane >> 4) * 8 + j;
            W2f[tid] = (cls < C_) ? f2bf(W2[k * C_ + cls]) : (unsigned short)0;
        }
        if (n == 0) *loss_out = 0.0f;
    }
}

// ---------------------------------------------------------------------------
// Fused head kernel, round 8: pipeline the staging INTO the K-loop.
// R7 profile: MfmaUtil 17%, HBM 8%, VALU 22% -> pure serialization: (a) a
// 192KB/block staging burst with a vmcnt(0)-draining __syncthreads, (b) a
// K-loop whose MFMA issue (240 cy/SIMD/k-step) sits under the per-XCD L2
// B-read time (~786 cy/k-step), (c) a 9-barrier 4-phase epilogue.
// Changes:
//  * A staged in SIX double-buffered K=128 chunks (2x16KB of the 96KB LDS):
//    chunk c+1's nontemporal global loads issue at the TOP of chunk c's
//    MFMAs, fp32->bf16 convert + ds_write at the bottom. HBM hides under
//    the K-loop instead of serializing with it.
//  * All barriers are raw "s_waitcnt lgkmcnt(0); s_barrier" — NO vmcnt
//    drain, so the distance-2 B-register prefetch and the A-chunk loads
//    stay in flight across barriers (T4: never drain vmcnt in the loop).
//  * Epilogue collapsed: all 16 waves write tanh into the full 96KB Hsh
//    at once (LDS free after last chunk), ONE barrier, then waves 0-3 run
//    the 24-step logit GEMM + softmax + loss. 9 syncthreads -> 2 barriers.
// Regs: acc 48 + bA/bB 24 + rg 8 + af 16 transient ≈ 110-125, cap 128 @
// __launch_bounds__(1024,4) — one block/CU, 16 waves.
// ---------------------------------------------------------------------------
__launch_bounds__(1024, 4)
__global__ void fused_head_kernel(const float* __restrict__ hidden,
                                  const unsigned short* __restrict__ W1f,
                                  const float* __restrict__ b1,
                                  const unsigned short* __restrict__ W2f,
                                  const float* __restrict__ b2,
                                  const int* __restrict__ labels,
                                  const int* __restrict__ epoch_p,
                                  float* __restrict__ probs,
                                  float* __restrict__ loss)
{
    __shared__ unsigned short Ash[24 * 4 * 512];   // 96 KB. K-loop: 2x16KB A-chunk dbuf at [0]/[8192]. Epilogue: full Hsh.

    const int tid  = threadIdx.x;
    const int w    = tid >> 6;     // wave 0..15
    const int lane = tid & 63;
    const int tok0 = blockIdx.x * BM_;
    const int c16  = lane & 15;
    const int q    = lane >> 4;

    // ---- staging geometry: thread handles rows tkA and tkA+32, float4 fq ----
    const f32x4* hsrc = (const f32x4*)(hidden + (size_t)tok0 * E_);
    const int tkA = tid >> 5;        // 0..31
    const int fq  = tid & 31;        // float4 index within the chunk's 32-float4 row segment
    const int t_l = fq >> 3;         // k-step 0..3 inside chunk   (k_local = 4*fq)
    const int jj  = (fq & 1) * 4;    // j = k_local & 7
    const int q2s = (fq >> 1) & 3;   // (k_local>>3)&3

    f32x4 rg0, rg1;                  // in-flight A chunk (distance-1)
    auto issue = [&](int c) {
        rg0 = __builtin_nontemporal_load(hsrc + (size_t)tkA * 192 + c * 32 + fq);
        rg1 = __builtin_nontemporal_load(hsrc + (size_t)(tkA + 32) * 192 + c * 32 + fq);
    };
    auto stage = [&](int bsel) {     // convert + ds_write into buffer bsel
        unsigned short* bufp = &Ash[bsel * 8192];
        {
            int lnf = (tkA & 15) + 16 * q2s;
            int mt  = tkA >> 4;
            ushort4 pk = { f2bf(rg0[0]), f2bf(rg0[1]), f2bf(rg0[2]), f2bf(rg0[3]) };
            *(ushort4*)(&bufp[((t_l * 4 + mt) * 64 + lnf) * 8 + jj]) = pk;
        }
        {
            int tk  = tkA + 32;
            int lnf = (tk & 15) + 16 * q2s;
            int mt  = tk >> 4;
            ushort4 pk = { f2bf(rg1[0]), f2bf(rg1[1]), f2bf(rg1[2]), f2bf(rg1[3]) };
            *(ushort4*)(&bufp[((t_l * 4 + mt) * 64 + lnf) * 8 + jj]) = pk;
        }
    };

    issue(0);                        // chunk 0 loads start immediately

    // ---- initial B prefetch (register-direct from L2-resident W1f) ----
    const unsigned short* Wp = W1f + (size_t)(w * 3 * 24) * 512 + lane * 8;
    bf16x8 bA[3], bB[3];
    #pragma unroll
    for (int i = 0; i < 3; ++i)
        bA[i] = __builtin_bit_cast(bf16x8, *(const i32x4*)(Wp + (i * 24 + 0) * 512));
    #pragma unroll
    for (int i = 0; i < 3; ++i)
        bB[i] = __builtin_bit_cast(bf16x8, *(const i32x4*)(Wp + (i * 24 + 1) * 512));

    const f32x4 zero4 = {0.0f, 0.0f, 0.0f, 0.0f};
    f32x4 acc[4][3];
    #pragma unroll
    for (int mt = 0; mt < 4; ++mt)
        #pragma unroll
        for (int nt = 0; nt < 3; ++nt) acc[mt][nt] = zero4;

    stage(0);                        // waits vmcnt for rg only (B loads are younger)
    asm volatile("s_waitcnt lgkmcnt(0)\ns_barrier" ::: "memory");

    // ---- K loop: 6 chunks x 4 k-steps; staging overlapped, barriers keep vmcnt live ----
    #pragma unroll
    for (int c = 0; c < 6; ++c) {
        const unsigned short* bufp = &Ash[(c & 1) * 8192];
        if (c < 5) issue(c + 1);     // next chunk in flight across this chunk's MFMAs
        #pragma unroll
        for (int tl = 0; tl < 2; ++tl) {
            const int tt = 2 * c + tl;
            // even k-step (local t = 2*tl): consume bA
            {
                bf16x8 af[4];
                #pragma unroll
                for (int mt = 0; mt < 4; ++mt)
                    af[mt] = __builtin_bit_cast(bf16x8,
                        *(const i32x4*)(&bufp[(((2 * tl) * 4 + mt) * 64 + lane) * 8]));
                #pragma unroll
                for (int mt = 0; mt < 4; ++mt)
                    #pragma unroll
                    for (int nt = 0; nt < 3; ++nt)
                        acc[mt][nt] = __builtin_amdgcn_mfma_f32_16x16x32_bf16(
                            af[mt], bA[nt], acc[mt][nt], 0, 0, 0);
            }
            if (tt < 11) {
                #pragma unroll
                for (int i = 0; i < 3; ++i)
                    bA[i] = __builtin_bit_cast(bf16x8,
                        *(const i32x4*)(Wp + (i * 24 + 2 * tt + 2) * 512));
            }
            // odd k-step (local t = 2*tl+1): consume bB
            {
                bf16x8 af[4];
                #pragma unroll
                for (int mt = 0; mt < 4; ++mt)
                    af[mt] = __builtin_bit_cast(bf16x8,
                        *(const i32x4*)(&bufp[(((2 * tl + 1) * 4 + mt) * 64 + lane) * 8]));
                #pragma unroll
                for (int mt = 0; mt < 4; ++mt)
                    #pragma unroll
                    for (int nt = 0; nt < 3; ++nt)
                        acc[mt][nt] = __builtin_amdgcn_mfma_f32_16x16x32_bf16(
                            af[mt], bB[nt], acc[mt][nt], 0, 0, 0);
            }
            if (tt < 11) {
                #pragma unroll
                for (int i = 0; i < 3; ++i)
                    bB[i] = __builtin_bit_cast(bf16x8,
                        *(const i32x4*)(Wp + (i * 24 + 2 * tt + 3) * 512));
            }
        }
        if (c < 5) stage((c + 1) & 1);
        // lgkm-only barrier: ds_writes visible; B prefetch + A loads stay in flight
        asm volatile("s_waitcnt lgkmcnt(0)\ns_barrier" ::: "memory");
    }

    // ---- epilogue: single pass. ALL 16 waves write tanh into full Hsh ----
    unsigned short* Hsh = &Ash[0];
    #pragma unroll
    for (int i = 0; i < 3; ++i) {
        int col = w * 48 + i * 16 + c16;        // global h-column 0..767
        float b1v = b1[col];
        int t2 = col >> 5;
        int q2 = (col >> 3) & 3;
        int j  = col & 7;
        #pragma unroll
        for (int mt = 0; mt < 4; ++mt) {
            #pragma unroll
            for (int r = 0; r < 4; ++r) {
                float z = acc[mt][i][r] + b1v;
                // tanh(z) = 1 - 2/(exp(2z)+1), exp via native exp2
                float e = exp2f(z * 2.8853900817779268f);
                float th = 1.0f - 2.0f * __builtin_amdgcn_rcpf(e + 1.0f);
                int lanep = (q * 4 + r) + 16 * q2;
                Hsh[((t2 * 4 + mt) * 64 + lanep) * 8 + j] = f2bf(th);
            }
        }
    }
    asm volatile("s_waitcnt lgkmcnt(0)\ns_barrier" ::: "memory");

    // ---- logit GEMM (24 straight k-steps) + softmax + probs + loss ----
    if (w < 4) {
        f32x4 logit = zero4;
        #pragma unroll
        for (int t2 = 0; t2 < 24; ++t2) {
            bf16x8 ha = __builtin_bit_cast(bf16x8, *(const i32x4*)(&Hsh[((t2 * 4 + w) * 64 + lane) * 8]));
            bf16x8 wb = __builtin_bit_cast(bf16x8, *(const i32x4*)(W2f + ((size_t)t2 * 64 + lane) * 8));
            logit = __builtin_amdgcn_mfma_f32_16x16x32_bf16(ha, wb, logit, 0, 0, 0);
        }

        const bool valid = (c16 < C_);
        const float b2v = valid ? b2[c16] : 0.0f;
        const int ep = epoch_p[0];
        float lsum = 0.0f;
        #pragma unroll
        for (int r = 0; r < 4; ++r) {
            float l = valid ? (logit[r] + b2v) : -3.0e38f;
            float m = l;
            #pragma unroll
            for (int d = 1; d < 16; d <<= 1)
                m = fmaxf(m, __shfl_xor(m, d, 64));
            float e = valid ? exp2f((l - m) * 1.44269504f) : 0.0f;
            float s = e;
            #pragma unroll
            for (int d = 1; d < 16; d <<= 1)
                s += __shfl_xor(s, d, 64);
            float p = e / s;
            int row = tok0 + w * 16 + q * 4 + r;
            if (valid) __builtin_nontemporal_store(p, &probs[(size_t)row * C_ + c16]);
            int lab = labels[row];
            if (valid && lab == c16) {
                float wgt = (ep <= 2) ? 1.0f : ((p > 0.7f) ? 1.0f : 0.0f);
                if (wgt > 0.0f)
                    lsum += (1.0f - exp2f(0.7f * log2f(p))) * (1.0f / 0.7f);
            }
        }
        #pragma unroll
        for (int d = 1; d < 64; d <<= 1)
            lsum += __shfl_xor(lsum, d, 64);
        if (lane == 0) atomicAdd(loss, lsum);
    }
}

// ---------------------------------------------------------------------------
extern "C" void kernel_launch(void* const* d_in, const int* in_sizes, int n_in,
                              void* d_out, int out_size, void* d_ws, size_t ws_size,
                              hipStream_t stream)
{
    const float* hidden = (const float*)d_in[0];
    const float* W1     = (const float*)d_in[1];
    const float* b1     = (const float*)d_in[2];
    const float* W2     = (const float*)d_in[3];
    const float* b2     = (const float*)d_in[4];
    const int*   labels = (const int*)d_in[5];
    const int*   epoch  = (const int*)d_in[6];

    float* probs = (float*)d_out;                       // [32768 x 9]
    float* loss  = probs + (size_t)M_TOTAL * C_;        // scalar at the end

    unsigned short* W1f = (unsigned short*)d_ws;        // 589824 bf16 (ntile-major)
    unsigned short* W2f = W1f + 48 * 24 * 512;          // 12288 bf16

    prep_kernel<<<769, 768, 0, stream>>>(W1, W2, W1f, W2f, loss);
    fused_head_kernel<<<M_TOTAL / BM_, 1024, 0, stream>>>(hidden, W1f, b1, W2f, b2,
                                                          labels, epoch, probs, loss);
}

// Round 4
// 214.633 us; speedup vs baseline: 1.0318x; 1.0229x over previous
//
#include <hip/hip_runtime.h>
#include <hip/hip_bf16.h>
#include <stdint.h>

#define E_ 768
#define H_ 768
#define C_ 9
#define M_TOTAL 32768
#define BM_ 64           // tokens per block

typedef __attribute__((ext_vector_type(8))) __bf16 bf16x8;
typedef __attribute__((ext_vector_type(4))) float f32x4;
typedef __attribute__((ext_vector_type(4))) int i32x4;

static_assert(sizeof(bf16x8) == 16, "bf16x8 must be 16B");

__device__ __forceinline__ unsigned short f2bf(float f) {
    __hip_bfloat16 h = __float2bfloat16(f);
    return __builtin_bit_cast(unsigned short, h);
}

// ---------------------------------------------------------------------------
// Prep (unchanged): W1 -> bf16 B-fragment cells, ntile-major; W2 -> padded
// B-frag cells; loss zeroed.
//   W1f[((ntile*24 + t)*64 + lane)*8 + j] = bf16(W1[k][n])
//     ntile=n>>4, t=k>>5, lane=(n&15)+16*((k>>3)&3), j=k&7
// ---------------------------------------------------------------------------
__global__ void prep_kernel(const float* __restrict__ W1, const float* __restrict__ W2,
                            unsigned short* __restrict__ W1f, unsigned short* __restrict__ W2f,
                            float* __restrict__ loss_out)
{
    int b = blockIdx.x;
    int n = threadIdx.x;
    if (b < 768) {
        int k = b;
        float v = W1[k * H_ + n];
        int ntile = n >> 4;
        int t = k >> 5;
        int lane = (n & 15) + 16 * ((k >> 3) & 3);
        int j = k & 7;
        W1f[((ntile * 24 + t) * 64 + lane) * 8 + j] = f2bf(v);
    } else {
        for (int it = 0; it < 16; ++it) {
            int tid = it * 768 + n;
            int j    = tid & 7;
            int lane = (tid >> 3) & 63;
            int t    = tid >> 9;
            int cls  = lane & 15;
            int k = t * 32 + (lane >> 4) * 8 + j;
            W2f[tid] = (cls < C_) ? f2bf(W2[k * C_ + cls]) : (unsigned short)0;
        }
        if (n == 0) *loss_out = 0.0f;
    }
}

// ---------------------------------------------------------------------------
// Fused head kernel, round 9 (3rd submit; two broker timeouts, never ran):
// break the lockstep.
// R8 post-mortem: all four pipes (MFMA 930cy, LDS 770cy, L1<-L2 1000cy, VALU
// ~500cy per k-step per CU) SERIALIZE -> ~4400cy/k-step, every counter ~20%.
// Root cause: only ONE af set live (VGPR=60), so every wave issues 4 ds_reads
// then stalls on lgkmcnt(0) before its MFMAs -- 16 waves do this in lockstep.
// Changes vs R8:
//  * af register DOUBLE-buffer (af[2][4], +16 VGPR): step t prefetches step
//    t+1's A-frags before t's MFMAs -> MFMA waits lgkmcnt(4) = no stall.
//    Chunk-boundary step0 re-read after each barrier (5 short stalls total).
//  * s_setprio(1) around each 12-MFMA cluster (T5) -- waves now sit at
//    different pipeline depths, scheduler favors MFMA-ready waves.
//  * stage(c+1) moved mid-chunk (after step tl==1) so the convert+ds_write
//    burst overlaps MFMAs instead of fronting the barrier.
// Regs: af 32 + b 24 + rg 8 + addr/misc ~12 ->  ~76 VGPR + 48 AGPR = 124
// (cap 128 @ 4 waves/SIMD). Barriers stay lgkm-only (vmcnt never drained).
// ---------------------------------------------------------------------------
__launch_bounds__(1024, 4)
__global__ void fused_head_kernel(const float* __restrict__ hidden,
                                  const unsigned short* __restrict__ W1f,
                                  const float* __restrict__ b1,
                                  const unsigned short* __restrict__ W2f,
                                  const float* __restrict__ b2,
                                  const int* __restrict__ labels,
                                  const int* __restrict__ epoch_p,
                                  float* __restrict__ probs,
                                  float* __restrict__ loss)
{
    __shared__ unsigned short Ash[24 * 4 * 512];   // 96 KB. K-loop: 2x16KB A-chunk dbuf at [0]/[8192]. Epilogue: full Hsh.

    const int tid  = threadIdx.x;
    const int w    = tid >> 6;     // wave 0..15
    const int lane = tid & 63;
    const int tok0 = blockIdx.x * BM_;
    const int c16  = lane & 15;
    const int q    = lane >> 4;

    // ---- staging geometry: thread handles rows tkA and tkA+32, float4 fq ----
    const f32x4* hsrc = (const f32x4*)(hidden + (size_t)tok0 * E_);
    const int tkA = tid >> 5;        // 0..31
    const int fq  = tid & 31;        // float4 index within the chunk's 32-float4 row segment
    const int t_l = fq >> 3;         // k-step 0..3 inside chunk   (k_local = 4*fq)
    const int jj  = (fq & 1) * 4;    // j = k_local & 7
    const int q2s = (fq >> 1) & 3;   // (k_local>>3)&3

    f32x4 rg0, rg1;                  // in-flight A chunk (distance-1)
    auto issue = [&](int c) {
        rg0 = __builtin_nontemporal_load(hsrc + (size_t)tkA * 192 + c * 32 + fq);
        rg1 = __builtin_nontemporal_load(hsrc + (size_t)(tkA + 32) * 192 + c * 32 + fq);
    };
    auto stage = [&](int bsel) {     // convert + ds_write into buffer bsel
        unsigned short* bufp = &Ash[bsel * 8192];
        {
            int lnf = (tkA & 15) + 16 * q2s;
            int mt  = tkA >> 4;
            ushort4 pk = { f2bf(rg0[0]), f2bf(rg0[1]), f2bf(rg0[2]), f2bf(rg0[3]) };
            *(ushort4*)(&bufp[((t_l * 4 + mt) * 64 + lnf) * 8 + jj]) = pk;
        }
        {
            int tk  = tkA + 32;
            int lnf = (tk & 15) + 16 * q2s;
            int mt  = tk >> 4;
            ushort4 pk = { f2bf(rg1[0]), f2bf(rg1[1]), f2bf(rg1[2]), f2bf(rg1[3]) };
            *(ushort4*)(&bufp[((t_l * 4 + mt) * 64 + lnf) * 8 + jj]) = pk;
        }
    };

    issue(0);                        // chunk 0 loads start immediately

    // ---- initial B prefetch (register-direct from L2-resident W1f) ----
    const unsigned short* Wp = W1f + (size_t)(w * 3 * 24) * 512 + lane * 8;
    bf16x8 b0[3], b1v_[3];           // even-step / odd-step B frags (dist-2 rotation)
    #pragma unroll
    for (int i = 0; i < 3; ++i)
        b0[i] = __builtin_bit_cast(bf16x8, *(const i32x4*)(Wp + (i * 24 + 0) * 512));
    #pragma unroll
    for (int i = 0; i < 3; ++i)
        b1v_[i] = __builtin_bit_cast(bf16x8, *(const i32x4*)(Wp + (i * 24 + 1) * 512));

    const f32x4 zero4 = {0.0f, 0.0f, 0.0f, 0.0f};
    f32x4 acc[4][3];
    #pragma unroll
    for (int mt = 0; mt < 4; ++mt)
        #pragma unroll
        for (int nt = 0; nt < 3; ++nt) acc[mt][nt] = zero4;

    stage(0);                        // waits vmcnt for rg only (B loads are younger)
    asm volatile("s_waitcnt lgkmcnt(0)\ns_barrier" ::: "memory");

    // ---- A-fragment register double-buffer ----
    bf16x8 af[2][4];
    {   // prologue: chunk 0, step 0
        const unsigned short* bufp = &Ash[0];
        #pragma unroll
        for (int mt = 0; mt < 4; ++mt)
            af[0][mt] = __builtin_bit_cast(bf16x8,
                *(const i32x4*)(&bufp[((0 * 4 + mt) * 64 + lane) * 8]));
    }

    // ---- K loop: 6 chunks x 4 k-steps; af dbuf'd, staging mid-chunk ----
    #pragma unroll
    for (int c = 0; c < 6; ++c) {
        const unsigned short* bufp = &Ash[(c & 1) * 8192];
        if (c < 5) issue(c + 1);     // next chunk HBM loads in flight across this chunk
        #pragma unroll
        for (int tl = 0; tl < 4; ++tl) {
            const int tt = 4 * c + tl;        // global k-step 0..23
            const int cur = tl & 1;
            // prefetch NEXT step's A frags before this step's MFMAs
            if (tl < 3) {
                #pragma unroll
                for (int mt = 0; mt < 4; ++mt)
                    af[cur ^ 1][mt] = __builtin_bit_cast(bf16x8,
                        *(const i32x4*)(&bufp[(((tl + 1) * 4 + mt) * 64 + lane) * 8]));
            }
            __builtin_amdgcn_s_setprio(1);
            if ((tt & 1) == 0) {
                #pragma unroll
                for (int mt = 0; mt < 4; ++mt)
                    #pragma unroll
                    for (int nt = 0; nt < 3; ++nt)
                        acc[mt][nt] = __builtin_amdgcn_mfma_f32_16x16x32_bf16(
                            af[cur][mt], b0[nt], acc[mt][nt], 0, 0, 0);
            } else {
                #pragma unroll
                for (int mt = 0; mt < 4; ++mt)
                    #pragma unroll
                    for (int nt = 0; nt < 3; ++nt)
                        acc[mt][nt] = __builtin_amdgcn_mfma_f32_16x16x32_bf16(
                            af[cur][mt], b1v_[nt], acc[mt][nt], 0, 0, 0);
            }
            __builtin_amdgcn_s_setprio(0);
            // refill the just-consumed parity with step tt+2 (dist-2)
            if (tt + 2 < 24) {
                if ((tt & 1) == 0) {
                    #pragma unroll
                    for (int i = 0; i < 3; ++i)
                        b0[i] = __builtin_bit_cast(bf16x8,
                            *(const i32x4*)(Wp + (i * 24 + tt + 2) * 512));
                } else {
                    #pragma unroll
                    for (int i = 0; i < 3; ++i)
                        b1v_[i] = __builtin_bit_cast(bf16x8,
                            *(const i32x4*)(Wp + (i * 24 + tt + 2) * 512));
                }
            }
            if (tl == 1 && c < 5) stage((c + 1) & 1);   // write burst overlaps MFMAs
        }
        // lgkm-only barrier: ds ops drained; B prefetch + A-chunk loads stay in flight
        asm volatile("s_waitcnt lgkmcnt(0)\ns_barrier" ::: "memory");
        if (c < 5) {   // chunk-boundary prologue: next chunk, step 0 into af[0]
            const unsigned short* bufn = &Ash[((c + 1) & 1) * 8192];
            #pragma unroll
            for (int mt = 0; mt < 4; ++mt)
                af[0][mt] = __builtin_bit_cast(bf16x8,
                    *(const i32x4*)(&bufn[((0 * 4 + mt) * 64 + lane) * 8]));
        }
    }

    // ---- epilogue: single pass. ALL 16 waves write tanh into full Hsh ----
    unsigned short* Hsh = &Ash[0];
    #pragma unroll
    for (int i = 0; i < 3; ++i) {
        int col = w * 48 + i * 16 + c16;        // global h-column 0..767
        float b1b = b1[col];
        int t2 = col >> 5;
        int q2 = (col >> 3) & 3;
        int j  = col & 7;
        #pragma unroll
        for (int mt = 0; mt < 4; ++mt) {
            #pragma unroll
            for (int r = 0; r < 4; ++r) {
                float z = acc[mt][i][r] + b1b;
                // tanh(z) = 1 - 2/(exp(2z)+1), exp via native exp2
                float e = exp2f(z * 2.8853900817779268f);
                float th = 1.0f - 2.0f * __builtin_amdgcn_rcpf(e + 1.0f);
                int lanep = (q * 4 + r) + 16 * q2;
                Hsh[((t2 * 4 + mt) * 64 + lanep) * 8 + j] = f2bf(th);
            }
        }
    }
    asm volatile("s_waitcnt lgkmcnt(0)\ns_barrier" ::: "memory");

    // ---- logit GEMM (24 straight k-steps) + softmax + probs + loss ----
    if (w < 4) {
        f32x4 logit = zero4;
        #pragma unroll
        for (int t2 = 0; t2 < 24; ++t2) {
            bf16x8 ha = __builtin_bit_cast(bf16x8, *(const i32x4*)(&Hsh[((t2 * 4 + w) * 64 + lane) * 8]));
            bf16x8 wb = __builtin_bit_cast(bf16x8, *(const i32x4*)(W2f + ((size_t)t2 * 64 + lane) * 8));
            logit = __builtin_amdgcn_mfma_f32_16x16x32_bf16(ha, wb, logit, 0, 0, 0);
        }

        const bool valid = (c16 < C_);
        const float b2v = valid ? b2[c16] : 0.0f;
        const int ep = epoch_p[0];
        float lsum = 0.0f;
        #pragma unroll
        for (int r = 0; r < 4; ++r) {
            float l = valid ? (logit[r] + b2v) : -3.0e38f;
            float m = l;
            #pragma unroll
            for (int d = 1; d < 16; d <<= 1)
                m = fmaxf(m, __shfl_xor(m, d, 64));
            float e = valid ? exp2f((l - m) * 1.44269504f) : 0.0f;
            float s = e;
            #pragma unroll
            for (int d = 1; d < 16; d <<= 1)
                s += __shfl_xor(s, d, 64);
            float p = e / s;
            int row = tok0 + w * 16 + q * 4 + r;
            if (valid) __builtin_nontemporal_store(p, &probs[(size_t)row * C_ + c16]);
            int lab = labels[row];
            if (valid && lab == c16) {
                float wgt = (ep <= 2) ? 1.0f : ((p > 0.7f) ? 1.0f : 0.0f);
                if (wgt > 0.0f)
                    lsum += (1.0f - exp2f(0.7f * log2f(p))) * (1.0f / 0.7f);
            }
        }
        #pragma unroll
        for (int d = 1; d < 64; d <<= 1)
            lsum += __shfl_xor(lsum, d, 64);
        if (lane == 0) atomicAdd(loss, lsum);
    }
}

// ---------------------------------------------------------------------------
extern "C" void kernel_launch(void* const* d_in, const int* in_sizes, int n_in,
                              void* d_out, int out_size, void* d_ws, size_t ws_size,
                              hipStream_t stream)
{
    const float* hidden = (const float*)d_in[0];
    const float* W1     = (const float*)d_in[1];
    const float* b1     = (const float*)d_in[2];
    const float* W2     = (const float*)d_in[3];
    const float* b2     = (const float*)d_in[4];
    const int*   labels = (const int*)d_in[5];
    const int*   epoch  = (const int*)d_in[6];

    float* probs = (float*)d_out;                       // [32768 x 9]
    float* loss  = probs + (size_t)M_TOTAL * C_;        // scalar at the end

    unsigned short* W1f = (unsigned short*)d_ws;        // 589824 bf16 (ntile-major)
    unsigned short* W2f = W1f + 48 * 24 * 512;          // 12288 bf16

    prep_kernel<<<769, 768, 0, stream>>>(W1, W2, W1f, W2f, loss);
    fused_head_kernel<<<M_TOTAL / BM_, 1024, 0, stream>>>(hidden, W1f, b1, W2f, b2,
                                                          labels, epoch, probs, loss);
}

// Round 9
// 212.759 us; speedup vs baseline: 1.0409x; 1.0088x over previous
//
#include <hip/hip_runtime.h>
#include <hip/hip_bf16.h>
#include <stdint.h>

#define E_ 768
#define H_ 768
#define C_ 9
#define M_TOTAL 32768
#define BM_ 32           // tokens per block (R10: halved -> 2 independent blocks/CU)

typedef __attribute__((ext_vector_type(8))) __bf16 bf16x8;
typedef __attribute__((ext_vector_type(4))) float f32x4;
typedef __attribute__((ext_vector_type(4))) int i32x4;

static_assert(sizeof(bf16x8) == 16, "bf16x8 must be 16B");

__device__ __forceinline__ unsigned short f2bf(float f) {
    __hip_bfloat16 h = __float2bfloat16(f);
    return __builtin_bit_cast(unsigned short, h);
}

// ---------------------------------------------------------------------------
// Prep (unchanged): W1 -> bf16 B-fragment cells, ntile-major; W2 -> padded
// B-frag cells; loss zeroed.
//   W1f[((ntile*24 + t)*64 + lane)*8 + j] = bf16(W1[k][n])
//     ntile=n>>4, t=k>>5, lane=(n&15)+16*((k>>3)&3), j=k&7
// ---------------------------------------------------------------------------
__global__ void prep_kernel(const float* __restrict__ W1, const float* __restrict__ W2,
                            unsigned short* __restrict__ W1f, unsigned short* __restrict__ W2f,
                            float* __restrict__ loss_out)
{
    int b = blockIdx.x;
    int n = threadIdx.x;
    if (b < 768) {
        int k = b;
        float v = W1[k * H_ + n];
        int ntile = n >> 4;
        int t = k >> 5;
        int lane = (n & 15) + 16 * ((k >> 3) & 3);
        int j = k & 7;
        W1f[((ntile * 24 + t) * 64 + lane) * 8 + j] = f2bf(v);
    } else {
        for (int it = 0; it < 16; ++it) {
            int tid = it * 768 + n;
            int j    = tid & 7;
            int lane = (tid >> 3) & 63;
            int t    = tid >> 9;
            int cls  = lane & 15;
            int k = t * 32 + (lane >> 4) * 8 + j;
            W2f[tid] = (cls < C_) ? f2bf(W2[k * C_ + cls]) : (unsigned short)0;
        }
        if (n == 0) *loss_out = 0.0f;
    }
}

// ---------------------------------------------------------------------------
// Fused head kernel, round 10 (5th submit; infra failures, never ran):
// TWO independent barrier domains per CU.
// R9 post-mortem: af-dbuf gave only -11% (79.3us, MfmaUtil 19.7). All 16
// waves share ONE block -> every chunk barrier re-synchronizes them to the
// same pipeline position; at any instant all waves use the SAME pipe (MFMA
// or LDS or L2) while the others idle. Per-wave ILP can't break that.
// Fix (m114 mechanism): 2 blocks/CU with INDEPENDENT barriers. BM=32,
// 512 thr (8 waves), 48KB LDS -> 2 blocks co-resident (16 waves = 4/SIMD).
// When block A drains at a barrier, block B's waves feed the pipes.
// Cost accepted as decisive experiment: per-block B-read of full W1f
// doubles per-CU B-L2 traffic (48->96KB/k-step). If this WINS, lockstep
// was dominant; if it regresses, L2-BW is binding -> fp8 next.
// Wave = 2mt x 6nt: acc 48 + bF 24 (dist-1 refill) + af-dbuf 16 + rg 8
// + addr ~15 = ~115 regs <= 128. Barriers stay lgkm-only.
// ---------------------------------------------------------------------------
__launch_bounds__(512, 4)
__global__ void fused_head_kernel(const float* __restrict__ hidden,
                                  const unsigned short* __restrict__ W1f,
                                  const float* __restrict__ b1,
                                  const unsigned short* __restrict__ W2f,
                                  const float* __restrict__ b2,
                                  const int* __restrict__ labels,
                                  const int* __restrict__ epoch_p,
                                  float* __restrict__ probs,
                                  float* __restrict__ loss)
{
    __shared__ unsigned short Ash[24 * 2 * 512];   // 48 KB. K-loop: 2x8KB A-chunk dbuf at [0]/[4096]. Epilogue: full Hsh.

    const int tid  = threadIdx.x;
    const int w    = tid >> 6;     // wave 0..7
    const int lane = tid & 63;
    const int tok0 = blockIdx.x * BM_;
    const int c16  = lane & 15;
    const int q    = lane >> 4;

    // ---- staging geometry: thread handles row tkA, two float4 (i=0,1) ----
    const f32x4* hsrc = (const f32x4*)(hidden + (size_t)tok0 * E_);
    const int tkA = tid >> 4;          // 0..31 (token row)
    const int fx  = tid & 15;          // base float4 index
    const int mtS = tkA >> 4;          // 0 or 1
    // per-i staging constants (i=0: fq=fx, i=1: fq=fx+16)
    const int tA_0 = fx >> 3,        tA_1 = (fx + 16) >> 3;
    const int jj_0 = (fx & 1) * 4,   jj_1 = jj_0;            // (fq&1) same for fq,fq+16
    const int q2_0 = (fx >> 1) & 3,  q2_1 = ((fx + 16) >> 1) & 3;
    const int lnf_0 = (tkA & 15) + 16 * q2_0;
    const int lnf_1 = (tkA & 15) + 16 * q2_1;

    f32x4 rgA, rgB;                    // in-flight A chunk
    auto issue = [&](int c) {
        rgA = __builtin_nontemporal_load(hsrc + (size_t)tkA * 192 + c * 32 + fx);
        rgB = __builtin_nontemporal_load(hsrc + (size_t)tkA * 192 + c * 32 + fx + 16);
    };
    auto stage = [&](int bsel) {       // convert + ds_write into buffer bsel
        unsigned short* bufp = &Ash[bsel * 4096];
        {
            ushort4 pk = { f2bf(rgA[0]), f2bf(rgA[1]), f2bf(rgA[2]), f2bf(rgA[3]) };
            *(ushort4*)(&bufp[((tA_0 * 2 + mtS) * 64 + lnf_0) * 8 + jj_0]) = pk;
        }
        {
            ushort4 pk = { f2bf(rgB[0]), f2bf(rgB[1]), f2bf(rgB[2]), f2bf(rgB[3]) };
            *(ushort4*)(&bufp[((tA_1 * 2 + mtS) * 64 + lnf_1) * 8 + jj_1]) = pk;
        }
    };

    issue(0);                          // chunk 0 loads start immediately

    // ---- B registers: 6 ntiles, single-buffered, dist-1 refill ----
    const unsigned short* Wp = W1f + (size_t)(w * 6 * 24) * 512 + lane * 8;
    bf16x8 bF[6];
    #pragma unroll
    for (int i = 0; i < 6; ++i)
        bF[i] = __builtin_bit_cast(bf16x8, *(const i32x4*)(Wp + (i * 24 + 0) * 512));

    const f32x4 zero4 = {0.0f, 0.0f, 0.0f, 0.0f};
    f32x4 acc[2][6];
    #pragma unroll
    for (int mt = 0; mt < 2; ++mt)
        #pragma unroll
        for (int nt = 0; nt < 6; ++nt) acc[mt][nt] = zero4;

    stage(0);
    asm volatile("s_waitcnt lgkmcnt(0)\ns_barrier" ::: "memory");

    // ---- A-fragment register double-buffer ----
    bf16x8 af[2][2];
    {
        const unsigned short* bufp = &Ash[0];
        #pragma unroll
        for (int mt = 0; mt < 2; ++mt)
            af[0][mt] = __builtin_bit_cast(bf16x8,
                *(const i32x4*)(&bufp[((0 * 2 + mt) * 64 + lane) * 8]));
    }

    // ---- K loop: 6 chunks x 4 k-steps ----
    #pragma unroll
    for (int c = 0; c < 6; ++c) {
        const unsigned short* bufp = &Ash[(c & 1) * 4096];
        if (c < 5) issue(c + 1);       // next chunk HBM loads in flight
        #pragma unroll
        for (int tl = 0; tl < 4; ++tl) {
            const int tt = 4 * c + tl;            // global k-step 0..23
            const int cur = tl & 1;
            if (tl < 3) {                         // prefetch next step's A frags
                #pragma unroll
                for (int mt = 0; mt < 2; ++mt)
                    af[cur ^ 1][mt] = __builtin_bit_cast(bf16x8,
                        *(const i32x4*)(&bufp[(((tl + 1) * 2 + mt) * 64 + lane) * 8]));
            }
            __builtin_amdgcn_s_setprio(1);
            #pragma unroll
            for (int mt = 0; mt < 2; ++mt)
                #pragma unroll
                for (int nt = 0; nt < 6; ++nt)
                    acc[mt][nt] = __builtin_amdgcn_mfma_f32_16x16x32_bf16(
                        af[cur][mt], bF[nt], acc[mt][nt], 0, 0, 0);
            __builtin_amdgcn_s_setprio(0);
            if (tt + 1 < 24) {                    // dist-1 B refill (WAR-safe: loads issue after MFMAs)
                #pragma unroll
                for (int i = 0; i < 6; ++i)
                    bF[i] = __builtin_bit_cast(bf16x8,
                        *(const i32x4*)(Wp + (i * 24 + tt + 1) * 512));
            }
            if (tl == 1 && c < 5) stage((c + 1) & 1);
        }
        asm volatile("s_waitcnt lgkmcnt(0)\ns_barrier" ::: "memory");
        if (c < 5) {                              // next chunk, step 0 into af[0]
            const unsigned short* bufn = &Ash[((c + 1) & 1) * 4096];
            #pragma unroll
            for (int mt = 0; mt < 2; ++mt)
                af[0][mt] = __builtin_bit_cast(bf16x8,
                    *(const i32x4*)(&bufn[((0 * 2 + mt) * 64 + lane) * 8]));
        }
    }

    // ---- epilogue: all 8 waves write tanh into full Hsh (48 KB) ----
    unsigned short* Hsh = &Ash[0];
    #pragma unroll
    for (int i = 0; i < 6; ++i) {
        int col = (w * 6 + i) * 16 + c16;          // global h-column 0..767
        float b1b = b1[col];
        int t2 = col >> 5;
        int q2 = (col >> 3) & 3;
        int j  = col & 7;
        #pragma unroll
        for (int mt = 0; mt < 2; ++mt) {
            #pragma unroll
            for (int r = 0; r < 4; ++r) {
                float z = acc[mt][i][r] + b1b;
                // tanh(z) = 1 - 2/(exp(2z)+1), exp via native exp2
                float e = exp2f(z * 2.8853900817779268f);
                float th = 1.0f - 2.0f * __builtin_amdgcn_rcpf(e + 1.0f);
                int lanep = (q * 4 + r) + 16 * q2;
                Hsh[((t2 * 2 + mt) * 64 + lanep) * 8 + j] = f2bf(th);
            }
        }
    }
    asm volatile("s_waitcnt lgkmcnt(0)\ns_barrier" ::: "memory");

    // ---- logit GEMM (24 straight k-steps, waves 0-1) + softmax + loss ----
    if (w < 2) {
        f32x4 logit = zero4;
        #pragma unroll
        for (int t2 = 0; t2 < 24; ++t2) {
            bf16x8 ha = __builtin_bit_cast(bf16x8, *(const i32x4*)(&Hsh[((t2 * 2 + w) * 64 + lane) * 8]));
            bf16x8 wb = __builtin_bit_cast(bf16x8, *(const i32x4*)(W2f + ((size_t)t2 * 64 + lane) * 8));
            logit = __builtin_amdgcn_mfma_f32_16x16x32_bf16(ha, wb, logit, 0, 0, 0);
        }

        const bool valid = (c16 < C_);
        const float b2v = valid ? b2[c16] : 0.0f;
        const int ep = epoch_p[0];
        float lsum = 0.0f;
        #pragma unroll
        for (int r = 0; r < 4; ++r) {
            float l = valid ? (logit[r] + b2v) : -3.0e38f;
            float m = l;
            #pragma unroll
            for (int d = 1; d < 16; d <<= 1)
                m = fmaxf(m, __shfl_xor(m, d, 64));
            float e = valid ? exp2f((l - m) * 1.44269504f) : 0.0f;
            float s = e;
            #pragma unroll
            for (int d = 1; d < 16; d <<= 1)
                s += __shfl_xor(s, d, 64);
            float p = e / s;
            int row = tok0 + w * 16 + q * 4 + r;
            if (valid) __builtin_nontemporal_store(p, &probs[(size_t)row * C_ + c16]);
            int lab = labels[row];
            if (valid && lab == c16) {
                float wgt = (ep <= 2) ? 1.0f : ((p > 0.7f) ? 1.0f : 0.0f);
                if (wgt > 0.0f)
                    lsum += (1.0f - exp2f(0.7f * log2f(p))) * (1.0f / 0.7f);
            }
        }
        #pragma unroll
        for (int d = 1; d < 64; d <<= 1)
            lsum += __shfl_xor(lsum, d, 64);
        if (lane == 0) atomicAdd(loss, lsum);
    }
}

// ---------------------------------------------------------------------------
extern "C" void kernel_launch(void* const* d_in, const int* in_sizes, int n_in,
                              void* d_out, int out_size, void* d_ws, size_t ws_size,
                              hipStream_t stream)
{
    const float* hidden = (const float*)d_in[0];
    const float* W1     = (const float*)d_in[1];
    const float* b1     = (const float*)d_in[2];
    const float* W2     = (const float*)d_in[3];
    const float* b2     = (const float*)d_in[4];
    const int*   labels = (const int*)d_in[5];
    const int*   epoch  = (const int*)d_in[6];

    float* probs = (float*)d_out;                       // [32768 x 9]
    float* loss  = probs + (size_t)M_TOTAL * C_;        // scalar at the end

    unsigned short* W1f = (unsigned short*)d_ws;        // 589824 bf16 (ntile-major)
    unsigned short* W2f = W1f + 48 * 24 * 512;          // 12288 bf16

    prep_kernel<<<769, 768, 0, stream>>>(W1, W2, W1f, W2f, loss);
    fused_head_kernel<<<M_TOTAL / BM_, 512, 0, stream>>>(hidden, W1f, b1, W2f, b2,
                                                         labels, epoch, probs, loss);
}